// Round 1
// 844.021 us; speedup vs baseline: 1.4355x; 1.4355x over previous
//
#include <hip/hip_runtime.h>
#include <cstdint>

#define Bn 64
#define Hn 1024
#define Sn 512
#define Vn 50257

typedef short short8 __attribute__((ext_vector_type(8)));
typedef float f32x4 __attribute__((ext_vector_type(4)));

__device__ inline float fast_exp2(float x){ return __builtin_amdgcn_exp2f(x); }
__device__ inline float fast_rcp(float x){ return __builtin_amdgcn_rcpf(x); }
__device__ inline float fast_tanh(float x){
  float e = fast_exp2(x * 2.8853900817779268f);
  return 1.0f - 2.0f*fast_rcp(e + 1.0f);
}
__device__ inline float fast_sigmoid(float x){
  return fast_rcp(1.0f + fast_exp2(-1.4426950408889634f*x));
}
__device__ inline unsigned int bf16rne(float f){
  unsigned int u = __float_as_uint(f);
  return (u + 0x7fffu + ((u>>16)&1u)) >> 16;
}
__device__ inline unsigned int bfpack(float lo, float hi){
  return bf16rne(lo) | (bf16rne(hi) << 16);
}

// ---------------- prep: gather x = emb[idx] and transpose x,h0 to [k/4][b][4] ----------------
__global__ void prep_kernel(const int* __restrict__ idx, const float4* __restrict__ emb,
                            const float4* __restrict__ h0, float4* __restrict__ xT4,
                            float4* __restrict__ hT4){
  int b = blockIdx.x; int t = threadIdx.x;
  int row = idx[b];
  xT4[t*64 + b] = emb[(long)row*256 + t];
  hT4[t*64 + b] = h0[b*256 + t];
}

// ---------------- convert We = W_attn[:, H:] to bf16 [g][k] ----------------
__global__ void conv_we_kernel(const float* __restrict__ W_attn, unsigned short* __restrict__ we){
  int id0 = blockIdx.x*1024 + threadIdx.x;
  #pragma unroll
  for (int i=0;i<4;i++){
    int id = id0 + i*256;
    int g = id >> 10, k = id & 1023;
    we[id] = (unsigned short)bf16rne(W_attn[g*2048 + 1024 + k]);
  }
}

__global__ void zero_kernel(float* __restrict__ p, int n){
  int id = blockIdx.x*256 + threadIdx.x;
  if (id < n) p[id] = 0.f;
}

// ---------------- LDS-staged fp32 GEMM, in-block K-split across 4 waves ----------------
// out[b][n] = sum_m A_m[b] . W_m[n]  (+bias)(tanh?)
// A layout: [k4][b][4] float4 (xT4-style). W: row-major [N][ws], row offset wo.
// Block: TRB output rows, 64 batches = lanes. Wave w owns K4-range [w*K4src/4, ...).
// W chunk (TRB rows x 64 floats) is reg-staged -> wave-private LDS double buffer,
// read back as wave-uniform (broadcast) ds_read_b128.
template<int TRB, int NM, bool DOTANH>
__global__ __launch_bounds__(256) void tile_gemm_f32(
    const float4* __restrict__ A0, const float* __restrict__ W0, int w0s,
    const float4* __restrict__ A1, const float* __restrict__ W1, int w1s, int w1o,
    const float* __restrict__ bias0, const float* __restrict__ bias1,
    float* __restrict__ out, int outStride, int K4src)
{
  constexpr int CH_K4 = 16;             // k4 per chunk (64 floats per row)
  constexpr int CH_F4 = TRB * CH_K4;    // float4s per chunk tile
  constexpr int LD = CH_F4 / 64;        // float4 loads per lane per chunk
  __shared__ float4 Wl[4][2][CH_F4];    // per-wave double buffer
  __shared__ float red[4][TRB][64];     // cross-wave reduction

  int tid = threadIdx.x; int l = tid & 63; int w = tid >> 6;
  int n0 = blockIdx.x * TRB;
  int K4w = K4src >> 2;
  int nch = K4w / CH_K4;
  int k4base = w * K4w;

  float acc[TRB];
  #pragma unroll
  for (int j=0;j<TRB;j++) acc[j]=0.f;

  for (int m=0; m<NM; m++){
    const float*  Wp = (m==0) ? W0 : W1;
    const float4* Ap = (m==0) ? A0 : A1;
    long ws = (m==0) ? w0s : w1s;
    long wo = (m==0) ? 0   : w1o;

    float4 r[LD];
    // preload chunk 0
    #pragma unroll
    for (int i=0;i<LD;i++){
      int idx = i*64 + l; int row = idx >> 4; int q = idx & 15;
      r[i] = *(const float4*)(Wp + (long)(n0+row)*ws + wo + (long)k4base*4 + q*4);
    }
    #pragma unroll
    for (int i=0;i<LD;i++){ int idx = i*64 + l; Wl[w][0][idx] = r[i]; }

    for (int c=0; c<nch; c++){
      int cur = c & 1;
      // issue next chunk's global loads early (latency hides under compute)
      if (c+1 < nch){
        #pragma unroll
        for (int i=0;i<LD;i++){
          int idx = i*64 + l; int row = idx >> 4; int q = idx & 15;
          r[i] = *(const float4*)(Wp + (long)(n0+row)*ws + wo + (long)(k4base + (c+1)*CH_K4)*4 + q*4);
        }
      }
      const float4* wb = &Wl[w][cur][0];
      int k4g = k4base + c*CH_K4;
      #pragma unroll
      for (int kk=0; kk<CH_K4; kk++){
        float4 a = Ap[(long)(k4g+kk)*64 + l];
        #pragma unroll
        for (int j=0;j<TRB;j++){
          float4 wv = wb[j*CH_K4 + kk];   // wave-uniform -> broadcast, conflict-free
          acc[j] = fmaf(a.x, wv.x, acc[j]);
          acc[j] = fmaf(a.y, wv.y, acc[j]);
          acc[j] = fmaf(a.z, wv.z, acc[j]);
          acc[j] = fmaf(a.w, wv.w, acc[j]);
        }
      }
      // write next chunk after compute of current (load has landed by now)
      if (c+1 < nch){
        #pragma unroll
        for (int i=0;i<LD;i++){ int idx = i*64 + l; Wl[w][cur^1][idx] = r[i]; }
      }
    }
  }

  // cross-wave K reduction + epilogue
  #pragma unroll
  for (int j=0;j<TRB;j++) red[w][j][l] = acc[j];
  __syncthreads();
  #pragma unroll
  for (int t2=0; t2<(TRB*64)/256; t2++){
    int idx = t2*256 + tid;
    int j  = idx & (TRB-1);
    int l2 = idx / TRB;
    float s = red[0][j][l2] + red[1][j][l2] + red[2][j][l2] + red[3][j][l2];
    int n = n0 + j;
    if (bias0) s += bias0[n];
    if (bias1) s += bias1[n];
    if (DOTANH) s = fast_tanh(s);
    out[(long)l2*outStride + n] = s;
  }
}

// ---------------- LSTM elementwise ----------------
__global__ void lstm_kernel(const float* __restrict__ gates, const float* __restrict__ c0,
                            float* __restrict__ h_out, float* __restrict__ c_out,
                            float* __restrict__ hT4){
  int id = blockIdx.x*256 + threadIdx.x;
  int b = id >> 10, h = id & 1023;
  const float* g = gates + (long)b*4096;
  float vi = g[h], vf = g[1024+h], vg = g[2048+h], vo = g[3072+h];
  float cp = c0[id];
  float cn = fast_sigmoid(vf)*cp + fast_sigmoid(vi)*fast_tanh(vg);
  float hn = fast_sigmoid(vo)*fast_tanh(cn);
  c_out[id] = cn; h_out[id] = hn;
  hT4[(h>>2)*256 + b*4 + (h&3)] = hn;
}

// ---------------- energy GEMM + tanh + v-dot, MFMA bf16 ----------------
__launch_bounds__(256, 2)
__global__ void attn_scores_kernel(const float4* __restrict__ enc, const unsigned short* __restrict__ we,
                                   const float* __restrict__ hWh, const float* __restrict__ vattn,
                                   float* __restrict__ scoresT)
{
  __shared__ unsigned short Asb[64*40];
  __shared__ unsigned short Bsb[256*40];
  int tid = threadIdx.x;
  int bid = blockIdx.x;
  int xcd = bid & 7, slot = bid >> 3;
  int s  = xcd*64 + (slot >> 2);
  int g0 = (slot & 3) * 256;
  int l = tid & 63, w = tid >> 6;
  int quad = l >> 4, l15 = l & 15;

  int arow = tid >> 2, aq = tid & 3;
  long abase = ((long)s*64 + arow)*256;

  f32x4 acc[4][4];
  #pragma unroll
  for (int mt=0;mt<4;mt++)
    #pragma unroll
    for (int gt=0;gt<4;gt++) acc[mt][gt] = 0.f;

  for (int kt=0; kt<32; kt++){
    __syncthreads();
    {
      float4 f0 = enc[abase + kt*8 + aq*2];
      float4 f1 = enc[abase + kt*8 + aq*2 + 1];
      uint4 p;
      p.x = bfpack(f0.x, f0.y); p.y = bfpack(f0.z, f0.w);
      p.z = bfpack(f1.x, f1.y); p.w = bfpack(f1.z, f1.w);
      *(uint4*)&Asb[arow*40 + aq*8] = p;
      #pragma unroll
      for (int p4=0;p4<4;p4++){
        int grow = p4*64 + (tid>>2);
        const uint4* src = (const uint4*)&we[(long)(g0+grow)*1024 + kt*32 + aq*8];
        *(uint4*)&Bsb[grow*40 + aq*8] = *src;
      }
    }
    __syncthreads();
    short8 af[4], bfr[4];
    #pragma unroll
    for (int mt=0;mt<4;mt++) af[mt]  = *(const short8*)&Asb[(mt*16 + l15)*40 + quad*8];
    #pragma unroll
    for (int gt=0;gt<4;gt++) bfr[gt] = *(const short8*)&Bsb[(w*64 + gt*16 + l15)*40 + quad*8];
    #pragma unroll
    for (int mt=0;mt<4;mt++)
      #pragma unroll
      for (int gt=0;gt<4;gt++)
        acc[mt][gt] = __builtin_amdgcn_mfma_f32_16x16x32_bf16(af[mt], bfr[gt], acc[mt][gt], 0,0,0);
  }

  float sp[16];
  #pragma unroll
  for (int i=0;i<16;i++) sp[i]=0.f;
  #pragma unroll
  for (int gt=0;gt<4;gt++){
    int g = g0 + w*64 + gt*16 + l15;
    float vg = vattn[g];
    #pragma unroll
    for (int mt=0;mt<4;mt++){
      #pragma unroll
      for (int r=0;r<4;r++){
        int b = mt*16 + quad*4 + r;
        float val = acc[mt][gt][r] + hWh[b*1024 + g];
        sp[mt*4+r] = fmaf(vg, fast_tanh(val), sp[mt*4+r]);
      }
    }
  }
  #pragma unroll
  for (int off=1; off<16; off<<=1){
    #pragma unroll
    for (int i=0;i<16;i++) sp[i] += __shfl_xor(sp[i], off);
  }
  if (l15 == 0){
    #pragma unroll
    for (int mt=0;mt<4;mt++)
      #pragma unroll
      for (int r=0;r<4;r++){
        int b = mt*16 + quad*4 + r;
        atomicAdd(&scoresT[s*64 + b], sp[mt*4+r]);
      }
  }
}

// ---------------- vocab GEMM: out[b][n] = concat[b] . W_out[n] + b_out[n], MFMA bf16 ----------------
__launch_bounds__(256, 2)
__global__ void vocab_gemm_kernel(const float* __restrict__ A, const float* __restrict__ W,
                                  const float* __restrict__ bias, float* __restrict__ out)
{
  __shared__ unsigned short Asb[64*40];
  __shared__ unsigned short Bsb[256*40];
  int tid = threadIdx.x;
  int n0 = blockIdx.x * 256;
  int l = tid & 63, w = tid >> 6;
  int quad = l >> 4, l15 = l & 15;

  int arow = tid >> 2, aq = tid & 3;   // A staging: 64 rows x 32 k
  int bkq = tid & 7;                   // B staging: 8 threads per row (float4 each)
  int brow = tid >> 3;                 // 32 rows per pass, 8 passes

  f32x4 acc[4][4];
  #pragma unroll
  for (int mt=0;mt<4;mt++)
    #pragma unroll
    for (int gt=0;gt<4;gt++) acc[mt][gt] = 0.f;

  for (int kt=0; kt<32; kt++){
    __syncthreads();
    {
      const float4* ap = (const float4*)&A[arow*1024 + kt*32 + aq*8];
      float4 f0 = ap[0], f1 = ap[1];
      uint4 p;
      p.x = bfpack(f0.x, f0.y); p.y = bfpack(f0.z, f0.w);
      p.z = bfpack(f1.x, f1.y); p.w = bfpack(f1.z, f1.w);
      *(uint4*)&Asb[arow*40 + aq*8] = p;
      #pragma unroll
      for (int p4=0;p4<8;p4++){
        int row = p4*32 + brow;
        int gr = n0 + row; if (gr >= Vn) gr = Vn-1;
        float4 f = *(const float4*)&W[(long)gr*1024 + kt*32 + bkq*4];
        uint2 q; q.x = bfpack(f.x, f.y); q.y = bfpack(f.z, f.w);
        *(uint2*)&Bsb[row*40 + bkq*4] = q;
      }
    }
    __syncthreads();
    short8 af[4], bfr[4];
    #pragma unroll
    for (int mt=0;mt<4;mt++) af[mt]  = *(const short8*)&Asb[(mt*16 + l15)*40 + quad*8];
    #pragma unroll
    for (int gt=0;gt<4;gt++) bfr[gt] = *(const short8*)&Bsb[(w*64 + gt*16 + l15)*40 + quad*8];
    #pragma unroll
    for (int mt=0;mt<4;mt++)
      #pragma unroll
      for (int gt=0;gt<4;gt++)
        acc[mt][gt] = __builtin_amdgcn_mfma_f32_16x16x32_bf16(af[mt], bfr[gt], acc[mt][gt], 0,0,0);
  }

  #pragma unroll
  for (int gt=0;gt<4;gt++){
    int n = n0 + w*64 + gt*16 + l15;
    if (n >= Vn) continue;
    float bz = bias[n];
    #pragma unroll
    for (int mt=0;mt<4;mt++){
      #pragma unroll
      for (int r=0;r<4;r++){
        int b = mt*16 + quad*4 + r;
        out[(long)b*Vn + n] = acc[mt][gt][r] + bz;
      }
    }
  }
}

// ---------------- softmax over b (axis=0) per s, apply mask ----------------
__global__ void softmax_b_kernel(float* __restrict__ a_sb, const float* __restrict__ mask){
  int tid = threadIdx.x; int l = tid & 63; int w = tid >> 6;
  int s = blockIdx.x*4 + w;
  float x = a_sb[s*64 + l];
  float m = x;
  #pragma unroll
  for (int off=1; off<64; off<<=1) m = fmaxf(m, __shfl_xor(m, off));
  float e = fast_exp2((x - m)*1.4426950408889634f);
  float t = e;
  #pragma unroll
  for (int off=1; off<64; off<<=1) t += __shfl_xor(t, off);
  float a = e * fast_rcp(t);
  a *= mask[s*64 + l];
  a_sb[s*64 + l] = a;
}

// ---------------- normalize over s per b; write alpha and aBS ----------------
__global__ void norm_s_kernel(const float* __restrict__ a_sb, float* __restrict__ aBS,
                              float* __restrict__ alpha){
  int b = blockIdx.x; int l = threadIdx.x;
  float tot = 0.f;
  #pragma unroll
  for (int i=0;i<8;i++) tot += a_sb[(l + i*64)*64 + b];
  #pragma unroll
  for (int off=1; off<64; off<<=1) tot += __shfl_xor(tot, off);
  float inv = 1.0f/(tot + 1e-10f);
  #pragma unroll
  for (int i=0;i<8;i++){
    int sidx = l + i*64;
    float v = a_sb[sidx*64 + b]*inv;
    aBS[b*512 + sidx] = v;
    alpha[b*512 + sidx] = v;
  }
}

// ---------------- context[b][h] = sum_s a[b][s]*enc[s][b][h] ----------------
__global__ void context_kernel(const float* __restrict__ aBS, const float* __restrict__ enc,
                               float* __restrict__ ctx_out, float* __restrict__ ctxT4){
  int h = blockIdx.x*256 + threadIdx.x;
  int b = blockIdx.y;
  const float* ab = aBS + b*512;
  float acc = 0.f;
  for (int s0=0; s0<512; s0+=16){
    float av[16], ev[16];
    #pragma unroll
    for (int i=0;i<16;i++) av[i] = ab[s0+i];
    #pragma unroll
    for (int i=0;i<16;i++) ev[i] = enc[((long)(s0+i)*64 + b)*1024 + h];
    #pragma unroll
    for (int i=0;i<16;i++) acc = fmaf(av[i], ev[i], acc);
  }
  ctx_out[b*1024 + h] = acc;
  ctxT4[(h>>2)*256 + b*4 + (h&3)] = acc;
}

extern "C" void kernel_launch(void* const* d_in, const int* in_sizes, int n_in,
                              void* d_out, int out_size, void* d_ws, size_t ws_size,
                              hipStream_t stream)
{
  const int*   idx    = (const int*)  d_in[0];
  const float* h0     = (const float*)d_in[2];
  const float* c0     = (const float*)d_in[3];
  const float* enc    = (const float*)d_in[4];
  const float* mask   = (const float*)d_in[5];
  const float* emb    = (const float*)d_in[6];
  const float* W_ih   = (const float*)d_in[7];
  const float* W_hh   = (const float*)d_in[8];
  const float* b_ih   = (const float*)d_in[9];
  const float* b_hh   = (const float*)d_in[10];
  const float* W_attn = (const float*)d_in[11];
  const float* v_attn = (const float*)d_in[12];
  const float* W_cat  = (const float*)d_in[13];
  const float* b_cat  = (const float*)d_in[14];
  const float* W_out  = (const float*)d_in[15];
  const float* b_out  = (const float*)d_in[16];

  float* out     = (float*)d_out;
  float* o_ctx   = out + (long)Bn*Vn;
  float* o_h     = o_ctx + Bn*Hn;
  float* o_c     = o_h + Bn*Hn;
  float* o_alpha = o_c + Bn*Hn;

  float* ws    = (float*)d_ws;
  float* xT4   = ws;               // 65536
  float* hT4   = xT4 + 65536;      // 65536
  float* gates = hT4 + 65536;      // 262144
  float* hnT4  = gates + 262144;   // 65536
  float* hWh   = hnT4 + 65536;     // 65536
  float* a_sb  = hWh + 65536;      // 32768
  float* aBS   = a_sb + 32768;     // 32768
  float* ctxT4 = aBS + 32768;      // 65536
  float* catRM = ctxT4 + 65536;    // 65536 (concat, row-major [64][1024])
  unsigned short* we_bf = (unsigned short*)(catRM + 65536); // 1M bf16 = 2 MB

  prep_kernel<<<64,256,0,stream>>>(idx, (const float4*)emb, (const float4*)h0,
                                   (float4*)xT4, (float4*)hT4);
  conv_we_kernel<<<1024,256,0,stream>>>(W_attn, we_bf);
  zero_kernel<<<128,256,0,stream>>>(a_sb, 32768);
  // gates = x@W_ih^T + h@W_hh^T + b_ih + b_hh   [64][4096]
  tile_gemm_f32<4,2,false><<<1024,256,0,stream>>>((const float4*)xT4, W_ih, 1024,
      (const float4*)hT4, W_hh, 1024, 0, b_ih, b_hh, gates, 4096, 256);
  lstm_kernel<<<256,256,0,stream>>>(gates, c0, o_h, o_c, hnT4);
  // hWh = h_new @ W_attn[:, :H]^T   [64][1024]
  tile_gemm_f32<4,1,false><<<256,256,0,stream>>>((const float4*)hnT4, W_attn, 2048,
      nullptr, nullptr, 0, 0, nullptr, nullptr, hWh, 1024, 256);
  attn_scores_kernel<<<2048,256,0,stream>>>((const float4*)enc, we_bf, hWh, v_attn, a_sb);
  softmax_b_kernel<<<128,256,0,stream>>>(a_sb, mask);
  norm_s_kernel<<<64,64,0,stream>>>(a_sb, aBS, o_alpha);
  context_kernel<<<dim3(4,64),256,0,stream>>>(aBS, enc, o_ctx, ctxT4);
  // concat = tanh(h@Wc1^T + ctx@Wc2^T + b_cat), row-major [64][1024]
  tile_gemm_f32<4,2,true><<<256,256,0,stream>>>((const float4*)hnT4, W_cat, 2048,
      (const float4*)ctxT4, W_cat, 2048, 1024, b_cat, nullptr, catRM, 1024, 256);
  // output = concat@W_out^T + b_out  (MFMA bf16, W fetched once coalesced)
  vocab_gemm_kernel<<<197,256,0,stream>>>(catRM, W_out, b_out, out);
}

// Round 2
// 753.759 us; speedup vs baseline: 1.6074x; 1.1197x over previous
//
#include <hip/hip_runtime.h>
#include <cstdint>

#define Bn 64
#define Hn 1024
#define Sn 512
#define Vn 50257

typedef short short8 __attribute__((ext_vector_type(8)));
typedef float f32x4 __attribute__((ext_vector_type(4)));

__device__ inline float fast_exp2(float x){ return __builtin_amdgcn_exp2f(x); }
__device__ inline float fast_rcp(float x){ return __builtin_amdgcn_rcpf(x); }
__device__ inline float fast_tanh(float x){
  float e = fast_exp2(x * 2.8853900817779268f);
  return 1.0f - 2.0f*fast_rcp(e + 1.0f);
}
__device__ inline float fast_sigmoid(float x){
  return fast_rcp(1.0f + fast_exp2(-1.4426950408889634f*x));
}
__device__ inline unsigned int bf16rne(float f){
  unsigned int u = __float_as_uint(f);
  return (u + 0x7fffu + ((u>>16)&1u)) >> 16;
}
__device__ inline unsigned int bfpack(float lo, float hi){
  return bf16rne(lo) | (bf16rne(hi) << 16);
}

// ---------------- prep: gather x = emb[idx] and transpose x,h0 to [k/4][b][4] ----------------
__global__ void prep_kernel(const int* __restrict__ idx, const float4* __restrict__ emb,
                            const float4* __restrict__ h0, float4* __restrict__ xT4,
                            float4* __restrict__ hT4){
  int b = blockIdx.x; int t = threadIdx.x;
  int row = idx[b];
  xT4[t*64 + b] = emb[(long)row*256 + t];
  hT4[t*64 + b] = h0[b*256 + t];
}

// ---------------- convert We = W_attn[:, H:] to bf16 [g][k] ----------------
__global__ void conv_we_kernel(const float* __restrict__ W_attn, unsigned short* __restrict__ we){
  int id0 = blockIdx.x*1024 + threadIdx.x;
  #pragma unroll
  for (int i=0;i<4;i++){
    int id = id0 + i*256;
    int g = id >> 10, k = id & 1023;
    we[id] = (unsigned short)bf16rne(W_attn[g*2048 + 1024 + k]);
  }
}

__global__ void zero_kernel(float* __restrict__ p, int n){
  int id = blockIdx.x*256 + threadIdx.x;
  if (id < n) p[id] = 0.f;
}

// ---------------- LDS-staged fp32 GEMM, in-block K-split across 4 waves ----------------
template<int TRB, int NM, bool DOTANH>
__global__ __launch_bounds__(256) void tile_gemm_f32(
    const float4* __restrict__ A0, const float* __restrict__ W0, int w0s,
    const float4* __restrict__ A1, const float* __restrict__ W1, int w1s, int w1o,
    const float* __restrict__ bias0, const float* __restrict__ bias1,
    float* __restrict__ out, int outStride, int K4src)
{
  constexpr int CH_K4 = 16;             // k4 per chunk (64 floats per row)
  constexpr int CH_F4 = TRB * CH_K4;    // float4s per chunk tile
  constexpr int LD = CH_F4 / 64;        // float4 loads per lane per chunk
  __shared__ float4 Wl[4][2][CH_F4];    // per-wave double buffer
  __shared__ float red[4][TRB][64];     // cross-wave reduction

  int tid = threadIdx.x; int l = tid & 63; int w = tid >> 6;
  int n0 = blockIdx.x * TRB;
  int K4w = K4src >> 2;
  int nch = K4w / CH_K4;
  int k4base = w * K4w;

  float acc[TRB];
  #pragma unroll
  for (int j=0;j<TRB;j++) acc[j]=0.f;

  for (int m=0; m<NM; m++){
    const float*  Wp = (m==0) ? W0 : W1;
    const float4* Ap = (m==0) ? A0 : A1;
    long ws = (m==0) ? w0s : w1s;
    long wo = (m==0) ? 0   : w1o;

    float4 r[LD];
    // preload chunk 0
    #pragma unroll
    for (int i=0;i<LD;i++){
      int idx = i*64 + l; int row = idx >> 4; int q = idx & 15;
      r[i] = *(const float4*)(Wp + (long)(n0+row)*ws + wo + (long)k4base*4 + q*4);
    }
    #pragma unroll
    for (int i=0;i<LD;i++){ int idx = i*64 + l; Wl[w][0][idx] = r[i]; }

    for (int c=0; c<nch; c++){
      int cur = c & 1;
      // issue next chunk's global loads early (latency hides under compute)
      if (c+1 < nch){
        #pragma unroll
        for (int i=0;i<LD;i++){
          int idx = i*64 + l; int row = idx >> 4; int q = idx & 15;
          r[i] = *(const float4*)(Wp + (long)(n0+row)*ws + wo + (long)(k4base + (c+1)*CH_K4)*4 + q*4);
        }
      }
      const float4* wb = &Wl[w][cur][0];
      int k4g = k4base + c*CH_K4;
      #pragma unroll
      for (int kk=0; kk<CH_K4; kk++){
        float4 a = Ap[(long)(k4g+kk)*64 + l];
        #pragma unroll
        for (int j=0;j<TRB;j++){
          float4 wv = wb[j*CH_K4 + kk];   // wave-uniform -> broadcast, conflict-free
          acc[j] = fmaf(a.x, wv.x, acc[j]);
          acc[j] = fmaf(a.y, wv.y, acc[j]);
          acc[j] = fmaf(a.z, wv.z, acc[j]);
          acc[j] = fmaf(a.w, wv.w, acc[j]);
        }
      }
      // write next chunk after compute of current (load has landed by now)
      if (c+1 < nch){
        #pragma unroll
        for (int i=0;i<LD;i++){ int idx = i*64 + l; Wl[w][cur^1][idx] = r[i]; }
      }
    }
  }

  // cross-wave K reduction + epilogue
  #pragma unroll
  for (int j=0;j<TRB;j++) red[w][j][l] = acc[j];
  __syncthreads();
  #pragma unroll
  for (int t2=0; t2<(TRB*64)/256; t2++){
    int idx = t2*256 + tid;
    int j  = idx & (TRB-1);
    int l2 = idx / TRB;
    float s = red[0][j][l2] + red[1][j][l2] + red[2][j][l2] + red[3][j][l2];
    int n = n0 + j;
    if (bias0) s += bias0[n];
    if (bias1) s += bias1[n];
    if (DOTANH) s = fast_tanh(s);
    out[(long)l2*outStride + n] = s;
  }
}

// ---------------- LSTM elementwise ----------------
__global__ void lstm_kernel(const float* __restrict__ gates, const float* __restrict__ c0,
                            float* __restrict__ h_out, float* __restrict__ c_out,
                            float* __restrict__ hT4){
  int id = blockIdx.x*256 + threadIdx.x;
  int b = id >> 10, h = id & 1023;
  const float* g = gates + (long)b*4096;
  float vi = g[h], vf = g[1024+h], vg = g[2048+h], vo = g[3072+h];
  float cp = c0[id];
  float cn = fast_sigmoid(vf)*cp + fast_sigmoid(vi)*fast_tanh(vg);
  float hn = fast_sigmoid(vo)*fast_tanh(cn);
  c_out[id] = cn; h_out[id] = hn;
  hT4[(h>>2)*256 + b*4 + (h&3)] = hn;
}

// ---------------- energy GEMM + tanh + v-dot, MFMA bf16 ----------------
__launch_bounds__(256, 2)
__global__ void attn_scores_kernel(const float4* __restrict__ enc, const unsigned short* __restrict__ we,
                                   const float* __restrict__ hWh, const float* __restrict__ vattn,
                                   float* __restrict__ scoresT)
{
  __shared__ unsigned short Asb[64*40];
  __shared__ unsigned short Bsb[256*40];
  int tid = threadIdx.x;
  int bid = blockIdx.x;
  int xcd = bid & 7, slot = bid >> 3;
  int s  = xcd*64 + (slot >> 2);
  int g0 = (slot & 3) * 256;
  int l = tid & 63, w = tid >> 6;
  int quad = l >> 4, l15 = l & 15;

  int arow = tid >> 2, aq = tid & 3;
  long abase = ((long)s*64 + arow)*256;

  f32x4 acc[4][4];
  #pragma unroll
  for (int mt=0;mt<4;mt++)
    #pragma unroll
    for (int gt=0;gt<4;gt++) acc[mt][gt] = 0.f;

  for (int kt=0; kt<32; kt++){
    __syncthreads();
    {
      float4 f0 = enc[abase + kt*8 + aq*2];
      float4 f1 = enc[abase + kt*8 + aq*2 + 1];
      uint4 p;
      p.x = bfpack(f0.x, f0.y); p.y = bfpack(f0.z, f0.w);
      p.z = bfpack(f1.x, f1.y); p.w = bfpack(f1.z, f1.w);
      *(uint4*)&Asb[arow*40 + aq*8] = p;
      #pragma unroll
      for (int p4=0;p4<4;p4++){
        int grow = p4*64 + (tid>>2);
        const uint4* src = (const uint4*)&we[(long)(g0+grow)*1024 + kt*32 + aq*8];
        *(uint4*)&Bsb[grow*40 + aq*8] = *src;
      }
    }
    __syncthreads();
    short8 af[4], bfr[4];
    #pragma unroll
    for (int mt=0;mt<4;mt++) af[mt]  = *(const short8*)&Asb[(mt*16 + l15)*40 + quad*8];
    #pragma unroll
    for (int gt=0;gt<4;gt++) bfr[gt] = *(const short8*)&Bsb[(w*64 + gt*16 + l15)*40 + quad*8];
    #pragma unroll
    for (int mt=0;mt<4;mt++)
      #pragma unroll
      for (int gt=0;gt<4;gt++)
        acc[mt][gt] = __builtin_amdgcn_mfma_f32_16x16x32_bf16(af[mt], bfr[gt], acc[mt][gt], 0,0,0);
  }

  float sp[16];
  #pragma unroll
  for (int i=0;i<16;i++) sp[i]=0.f;
  #pragma unroll
  for (int gt=0;gt<4;gt++){
    int g = g0 + w*64 + gt*16 + l15;
    float vg = vattn[g];
    #pragma unroll
    for (int mt=0;mt<4;mt++){
      #pragma unroll
      for (int r=0;r<4;r++){
        int b = mt*16 + quad*4 + r;
        float val = acc[mt][gt][r] + hWh[b*1024 + g];
        sp[mt*4+r] = fmaf(vg, fast_tanh(val), sp[mt*4+r]);
      }
    }
  }
  #pragma unroll
  for (int off=1; off<16; off<<=1){
    #pragma unroll
    for (int i=0;i<16;i++) sp[i] += __shfl_xor(sp[i], off);
  }
  if (l15 == 0){
    #pragma unroll
    for (int mt=0;mt<4;mt++)
      #pragma unroll
      for (int r=0;r<4;r++){
        int b = mt*16 + quad*4 + r;
        atomicAdd(&scoresT[s*64 + b], sp[mt*4+r]);
      }
  }
}

// ---------------- vocab GEMM v2: N-tile 64, register-prefetch double-buffered LDS ----------------
// out[b][n] = concat[b] . W_out[n] + b_out[n].  Grid = ceil(V/64) = 786 blocks (~3/CU).
// Per kt (k-chunk of 32): stage A(64x32) and W(64x32) fp32->bf16. kt+1 global loads are
// issued before kt's MFMA so HBM latency hides under compute + TLP (12 waves/CU).
__global__ __launch_bounds__(256) void vocab_gemm_kernel(
    const float* __restrict__ A, const float* __restrict__ W,
    const float* __restrict__ bias, float* __restrict__ out)
{
  __shared__ unsigned short Asb[2][64*40];
  __shared__ unsigned short Bsb[2][64*40];
  int tid = threadIdx.x;
  int n0 = blockIdx.x * 64;
  int l = tid & 63, w = tid >> 6;
  int quad = l >> 4, l15 = l & 15;

  int arow = tid >> 2, aq = tid & 3;          // 64 rows x 4 threads, 8 floats each
  int gr = n0 + arow; if (gr >= Vn) gr = Vn-1;
  const float* arp = A + arow*1024 + aq*8;
  const float* brp = W + (long)gr*1024 + aq*8;

  f32x4 acc[4];
  #pragma unroll
  for (int mt=0;mt<4;mt++) acc[mt] = 0.f;

  float4 a0, a1, b0, b1;
  // preload kt=0
  a0 = *(const float4*)(arp + 0);
  a1 = *(const float4*)(arp + 4);
  b0 = *(const float4*)(brp + 0);
  b1 = *(const float4*)(brp + 4);
  {
    uint4 p;
    p.x = bfpack(a0.x, a0.y); p.y = bfpack(a0.z, a0.w);
    p.z = bfpack(a1.x, a1.y); p.w = bfpack(a1.z, a1.w);
    *(uint4*)&Asb[0][arow*40 + aq*8] = p;
    uint4 q;
    q.x = bfpack(b0.x, b0.y); q.y = bfpack(b0.z, b0.w);
    q.z = bfpack(b1.x, b1.y); q.w = bfpack(b1.z, b1.w);
    *(uint4*)&Bsb[0][arow*40 + aq*8] = q;
  }
  __syncthreads();

  for (int kt=0; kt<32; kt++){
    int cur = kt & 1;
    if (kt < 31){
      a0 = *(const float4*)(arp + (kt+1)*32 + 0);
      a1 = *(const float4*)(arp + (kt+1)*32 + 4);
      b0 = *(const float4*)(brp + (kt+1)*32 + 0);
      b1 = *(const float4*)(brp + (kt+1)*32 + 4);
    }
    short8 af[4], bf;
    #pragma unroll
    for (int mt=0;mt<4;mt++) af[mt] = *(const short8*)&Asb[cur][(mt*16 + l15)*40 + quad*8];
    bf = *(const short8*)&Bsb[cur][(w*16 + l15)*40 + quad*8];
    #pragma unroll
    for (int mt=0;mt<4;mt++)
      acc[mt] = __builtin_amdgcn_mfma_f32_16x16x32_bf16(af[mt], bf, acc[mt], 0,0,0);
    __syncthreads();
    if (kt < 31){
      uint4 p;
      p.x = bfpack(a0.x, a0.y); p.y = bfpack(a0.z, a0.w);
      p.z = bfpack(a1.x, a1.y); p.w = bfpack(a1.z, a1.w);
      *(uint4*)&Asb[cur^1][arow*40 + aq*8] = p;
      uint4 q;
      q.x = bfpack(b0.x, b0.y); q.y = bfpack(b0.z, b0.w);
      q.z = bfpack(b1.x, b1.y); q.w = bfpack(b1.z, b1.w);
      *(uint4*)&Bsb[cur^1][arow*40 + aq*8] = q;
      __syncthreads();
    }
  }

  // epilogue: out[b][n] = acc + bias[n]
  int n = n0 + w*16 + l15;
  if (n < Vn){
    float bz = bias[n];
    #pragma unroll
    for (int mt=0;mt<4;mt++){
      #pragma unroll
      for (int r=0;r<4;r++){
        int b = mt*16 + quad*4 + r;
        out[(long)b*Vn + n] = acc[mt][r] + bz;
      }
    }
  }
}

// ---------------- softmax over b (axis=0) per s, apply mask ----------------
__global__ void softmax_b_kernel(float* __restrict__ a_sb, const float* __restrict__ mask){
  int tid = threadIdx.x; int l = tid & 63; int w = tid >> 6;
  int s = blockIdx.x*4 + w;
  float x = a_sb[s*64 + l];
  float m = x;
  #pragma unroll
  for (int off=1; off<64; off<<=1) m = fmaxf(m, __shfl_xor(m, off));
  float e = fast_exp2((x - m)*1.4426950408889634f);
  float t = e;
  #pragma unroll
  for (int off=1; off<64; off<<=1) t += __shfl_xor(t, off);
  float a = e * fast_rcp(t);
  a *= mask[s*64 + l];
  a_sb[s*64 + l] = a;
}

// ---------------- normalize over s per b; write alpha and aBS ----------------
__global__ void norm_s_kernel(const float* __restrict__ a_sb, float* __restrict__ aBS,
                              float* __restrict__ alpha){
  int b = blockIdx.x; int l = threadIdx.x;
  float tot = 0.f;
  #pragma unroll
  for (int i=0;i<8;i++) tot += a_sb[(l + i*64)*64 + b];
  #pragma unroll
  for (int off=1; off<64; off<<=1) tot += __shfl_xor(tot, off);
  float inv = 1.0f/(tot + 1e-10f);
  #pragma unroll
  for (int i=0;i<8;i++){
    int sidx = l + i*64;
    float v = a_sb[sidx*64 + b]*inv;
    aBS[b*512 + sidx] = v;
    alpha[b*512 + sidx] = v;
  }
}

// ---------------- context[b][h] = sum_s a[b][s]*enc[s][b][h] ----------------
__global__ void context_kernel(const float* __restrict__ aBS, const float* __restrict__ enc,
                               float* __restrict__ ctx_out, float* __restrict__ ctxT4){
  int h = blockIdx.x*256 + threadIdx.x;
  int b = blockIdx.y;
  const float* ab = aBS + b*512;
  float acc = 0.f;
  for (int s0=0; s0<512; s0+=16){
    float av[16], ev[16];
    #pragma unroll
    for (int i=0;i<16;i++) av[i] = ab[s0+i];
    #pragma unroll
    for (int i=0;i<16;i++) ev[i] = enc[((long)(s0+i)*64 + b)*1024 + h];
    #pragma unroll
    for (int i=0;i<16;i++) acc = fmaf(av[i], ev[i], acc);
  }
  ctx_out[b*1024 + h] = acc;
  ctxT4[(h>>2)*256 + b*4 + (h&3)] = acc;
}

extern "C" void kernel_launch(void* const* d_in, const int* in_sizes, int n_in,
                              void* d_out, int out_size, void* d_ws, size_t ws_size,
                              hipStream_t stream)
{
  const int*   idx    = (const int*)  d_in[0];
  const float* h0     = (const float*)d_in[2];
  const float* c0     = (const float*)d_in[3];
  const float* enc    = (const float*)d_in[4];
  const float* mask   = (const float*)d_in[5];
  const float* emb    = (const float*)d_in[6];
  const float* W_ih   = (const float*)d_in[7];
  const float* W_hh   = (const float*)d_in[8];
  const float* b_ih   = (const float*)d_in[9];
  const float* b_hh   = (const float*)d_in[10];
  const float* W_attn = (const float*)d_in[11];
  const float* v_attn = (const float*)d_in[12];
  const float* W_cat  = (const float*)d_in[13];
  const float* b_cat  = (const float*)d_in[14];
  const float* W_out  = (const float*)d_in[15];
  const float* b_out  = (const float*)d_in[16];

  float* out     = (float*)d_out;
  float* o_ctx   = out + (long)Bn*Vn;
  float* o_h     = o_ctx + Bn*Hn;
  float* o_c     = o_h + Bn*Hn;
  float* o_alpha = o_c + Bn*Hn;

  float* ws    = (float*)d_ws;
  float* xT4   = ws;               // 65536
  float* hT4   = xT4 + 65536;      // 65536
  float* gates = hT4 + 65536;      // 262144
  float* hnT4  = gates + 262144;   // 65536
  float* hWh   = hnT4 + 65536;     // 65536
  float* a_sb  = hWh + 65536;      // 32768
  float* aBS   = a_sb + 32768;     // 32768
  float* ctxT4 = aBS + 32768;      // 65536
  float* catRM = ctxT4 + 65536;    // 65536 (concat, row-major [64][1024])
  unsigned short* we_bf = (unsigned short*)(catRM + 65536); // 1M bf16 = 2 MB

  prep_kernel<<<64,256,0,stream>>>(idx, (const float4*)emb, (const float4*)h0,
                                   (float4*)xT4, (float4*)hT4);
  conv_we_kernel<<<1024,256,0,stream>>>(W_attn, we_bf);
  zero_kernel<<<128,256,0,stream>>>(a_sb, 32768);
  // gates = x@W_ih^T + h@W_hh^T + b_ih + b_hh   [64][4096]
  tile_gemm_f32<4,2,false><<<1024,256,0,stream>>>((const float4*)xT4, W_ih, 1024,
      (const float4*)hT4, W_hh, 1024, 0, b_ih, b_hh, gates, 4096, 256);
  lstm_kernel<<<256,256,0,stream>>>(gates, c0, o_h, o_c, hnT4);
  // hWh = h_new @ W_attn[:, :H]^T   [64][1024]
  tile_gemm_f32<4,1,false><<<256,256,0,stream>>>((const float4*)hnT4, W_attn, 2048,
      nullptr, nullptr, 0, 0, nullptr, nullptr, hWh, 1024, 256);
  attn_scores_kernel<<<2048,256,0,stream>>>((const float4*)enc, we_bf, hWh, v_attn, a_sb);
  softmax_b_kernel<<<128,256,0,stream>>>(a_sb, mask);
  norm_s_kernel<<<64,64,0,stream>>>(a_sb, aBS, o_alpha);
  context_kernel<<<dim3(4,64),256,0,stream>>>(aBS, enc, o_ctx, ctxT4);
  // concat = tanh(h@Wc1^T + ctx@Wc2^T + b_cat), row-major [64][1024]
  tile_gemm_f32<4,2,true><<<256,256,0,stream>>>((const float4*)hnT4, W_cat, 2048,
      (const float4*)ctxT4, W_cat, 2048, 1024, b_cat, nullptr, catRM, 1024, 256);
  // output = concat@W_out^T + b_out  (MFMA bf16)
  vocab_gemm_kernel<<<786,256,0,stream>>>(catRM, W_out, b_out, out);
}